// Round 1
// baseline (67.151 us; speedup 1.0000x reference)
//
#include <hip/hip_runtime.h>

// MLSA-style multi-stage time-varying FIR.
// Per stage a=1..20: xa[t] = (1/a) * sum_{k=0..24} xa_prev[t-k]*mc[t,k], y = x + sum xa.
//
// vs previous version: the kernel was latency/occupancy-bound (244 blocks = 488
// waves on 1024 SIMDs = 0.48 waves/SIMD; runtime ~= naked 20-stage serial
// latency). This version trades redundant halo compute for parallelism:
//   HALO 240 -> 120  (truncation first leaks at stage 6; leaked gain
//                     ~ prod_{a=1..5} 0.49/a ~ 2e-5 << 0.107 threshold)
//   R 4 -> 2, NT=128 (P=256, VALID=136 -> 121 tiles x 4 = 484 blocks,
//                     968 waves; per-stage per-thread work halves; ~100 VGPR)
// Inner product split into two independent chains (13+12 FMAs) to halve the
// per-stage dependent-FMA latency. LDS exchange: float2 slots, 1 ds_write_b64
// + 12 float2 reads (compiler merges to ds_read2_b64), 24-float zero left pad.

#define T_LEN  16384
#define B_N    4
#define M      25
#define STAGES 20
#define HALO   120
#define NT     128
#define R      2
#define P      (NT * R)       // 256 points per block
#define VALID  (P - HALO)     // 136 valid outputs per block
#define PADS   12             // float2 zero-pad slots = 24 floats of history

typedef float v2f __attribute__((ext_vector_type(2)));

__global__ __launch_bounds__(NT, 1)
void mlsa_fir_kernel(const float* __restrict__ x,
                     const float* __restrict__ mc,
                     float* __restrict__ out) {
    // double-buffered xa exchange; slot s holds points p0_block + 2*(s-PADS)
    __shared__ float2 sbuf[2][PADS + NT];

    const int tid = threadIdx.x;
    const int b   = blockIdx.y;
    const int t0  = blockIdx.x * VALID - HALO;  // global t of local point 0
    const int p0  = t0 + R * tid;               // this thread's first point (even)

    // clamped base so loads stay in-bounds; p0 is even, rows zeroed below if OOB
    const int ps = p0 < 0 ? 0 : (p0 > T_LEN - R ? T_LEN - R : p0);

    // ---- coefficients: 50 contiguous floats (2 rows x 25), 8B-aligned ----
    float flat[R * M];
    {
        const float* src = mc + ((size_t)b * T_LEN + ps) * M;
        #pragma unroll
        for (int j = 0; j < (R * M) / 2; ++j) {
            float2 v = *reinterpret_cast<const float2*>(src + 2 * j);
            flat[2*j+0] = v.x; flat[2*j+1] = v.y;
        }
        #pragma unroll
        for (int i = 0; i < R; ++i) {
            const int ti = p0 + i;
            if (ti < 0 || ti >= T_LEN) {
                #pragma unroll
                for (int k = 0; k < M; ++k) flat[M*i + k] = 0.0f;
            }
        }
    }
    // interleave for packed math: c01[k] = {c[pt0][k], c[pt1][k]}
    v2f c01[M];
    #pragma unroll
    for (int k = 0; k < M; ++k) {
        c01[k] = (v2f){flat[k], flat[M + k]};
    }

    // ---- x: one aligned float2 ----
    float w[26];   // w[0..23] = 24 preceding values (from LDS), w[24..25] = own
    v2f y01;
    {
        float2 xl = *reinterpret_cast<const float2*>(x + (size_t)b * T_LEN + ps);
        float xv[R] = {xl.x, xl.y};
        #pragma unroll
        for (int i = 0; i < R; ++i) {
            const int ti = p0 + i;
            if (ti < 0 || ti >= T_LEN) xv[i] = 0.0f;
            w[24 + i] = xv[i];
        }
        y01 = (v2f){xv[0], xv[1]};
    }

    // zero the left pad of both buffers (visibility ordered by the loop's first barrier)
    if (tid < PADS) {
        sbuf[0][tid] = make_float2(0.f, 0.f);
        sbuf[1][tid] = make_float2(0.f, 0.f);
    }

    #pragma unroll
    for (int a = 1; a <= STAGES; ++a) {
        float2* buf = sbuf[(a - 1) & 1];
        buf[PADS + tid] = make_float2(w[24], w[25]);
        __syncthreads();
        #pragma unroll
        for (int j = 0; j < PADS; ++j) {
            float2 h = buf[tid + j];          // floats [2*tid-24+2j .. +1]
            w[2*j+0] = h.x; w[2*j+1] = h.y;
        }
        const float inv = 1.0f / (float)a;
        // two independent accumulation chains (13 + 12 deps) -> shorter critical path
        v2f accA = (v2f){0.f, 0.f}, accB = (v2f){0.f, 0.f};
        #pragma unroll
        for (int k = 0; k < M; k += 2) {
            v2f wpA = (v2f){w[24 - k], w[25 - k]};
            accA += c01[k] * wpA;             // ffp-contract -> v_pk_fma_f32
            if (k + 1 < M) {
                v2f wpB = (v2f){w[23 - k], w[24 - k]};
                accB += c01[k + 1] * wpB;
            }
        }
        v2f s01 = (accA + accB) * inv;
        w[24] = s01.x; w[25] = s01.y;
        y01 += s01;
        // no second barrier: next stage writes the OTHER buffer; its barrier
        // orders this stage's reads vs the stage-after-next's writes
    }

    // ---- store valid region ----
    if (tid >= HALO / R && p0 < T_LEN) {
        float* dst = out + (size_t)b * T_LEN + p0;
        *reinterpret_cast<float2*>(dst) = make_float2(y01.x, y01.y);  // p0 even, T even
    }
}

extern "C" void kernel_launch(void* const* d_in, const int* in_sizes, int n_in,
                              void* d_out, int out_size, void* d_ws, size_t ws_size,
                              hipStream_t stream) {
    const float* x  = (const float*)d_in[0];
    const float* mc = (const float*)d_in[1];
    float* out = (float*)d_out;

    const int num_tiles = (T_LEN + VALID - 1) / VALID;  // 121
    dim3 grid(num_tiles, B_N);                           // 484 blocks
    mlsa_fir_kernel<<<grid, NT, 0, stream>>>(x, mc, out);
}